// Round 4
// baseline (937.597 us; speedup 1.0000x reference)
//
#include <hip/hip_runtime.h>
#include <math.h>

#define B 64
#define D 1024
#define H 16
#define DH 64
#define T 511
#define TT 512          // T+1
#define SMEM 256        // cross-attn memory length
#define DFF 4096
#define NLAYER 4
#define SCALE 0.125f
#define EPS 1e-5f

__device__ __forceinline__ float dot4(const float4 a, const float4 b) {
    return a.x * b.x + a.y * b.y + a.z * b.z + a.w * b.w;
}
__device__ __forceinline__ float4 f4add(float4 a, float4 b) {
    return make_float4(a.x + b.x, a.y + b.y, a.z + b.z, a.w + b.w);
}

// ---------------------------------------------------------------------------
// Batch-shared GEMM: P[ks][64][O] = A[64][K-slice] @ W[O][K-slice]^T
// grid (O/128, KS), block 256. Thread tile 4b x 8o.
// ---------------------------------------------------------------------------
template <int K, int KS>
__global__ __launch_bounds__(256) void gemm_proj(
    const float* __restrict__ A,   // [64][K]
    const float* __restrict__ W,   // [O][K] row-major
    float* __restrict__ P)         // [KS][64][O]
{
    constexpr int KSUB = K / KS;
    const int O = gridDim.x * 128;
    const int obase = blockIdx.x * 128;
    const int kb = blockIdx.y * KSUB;
    const int tid = threadIdx.x;

    __shared__ float As[32][68];
    __shared__ float Ws[32][132];

    const int b0 = (tid >> 4) * 4;
    const int o0 = (tid & 15) * 8;

    float acc[4][8];
#pragma unroll
    for (int i = 0; i < 4; ++i)
#pragma unroll
        for (int j = 0; j < 8; ++j) acc[i][j] = 0.f;

    for (int kc = 0; kc < KSUB; kc += 32) {
#pragma unroll
        for (int j = 0; j < 2; ++j) {
            const int f = tid + 256 * j;
            const int bb = f >> 3, k4 = f & 7;
            const float4 v = *reinterpret_cast<const float4*>(
                A + (size_t)bb * K + kb + kc + 4 * k4);
            As[4 * k4 + 0][bb] = v.x; As[4 * k4 + 1][bb] = v.y;
            As[4 * k4 + 2][bb] = v.z; As[4 * k4 + 3][bb] = v.w;
        }
#pragma unroll
        for (int j = 0; j < 4; ++j) {
            const int f = tid + 256 * j;
            const int oo = f >> 3, k4 = f & 7;
            const float4 v = *reinterpret_cast<const float4*>(
                W + (size_t)(obase + oo) * K + kb + kc + 4 * k4);
            Ws[4 * k4 + 0][oo] = v.x; Ws[4 * k4 + 1][oo] = v.y;
            Ws[4 * k4 + 2][oo] = v.z; Ws[4 * k4 + 3][oo] = v.w;
        }
        __syncthreads();
#pragma unroll 8
        for (int k = 0; k < 32; ++k) {
            const float4 av = *reinterpret_cast<const float4*>(&As[k][b0]);
            const float4 w0 = *reinterpret_cast<const float4*>(&Ws[k][o0]);
            const float4 w1 = *reinterpret_cast<const float4*>(&Ws[k][o0 + 4]);
            const float a[4] = {av.x, av.y, av.z, av.w};
            const float w[8] = {w0.x, w0.y, w0.z, w0.w, w1.x, w1.y, w1.z, w1.w};
#pragma unroll
            for (int i = 0; i < 4; ++i)
#pragma unroll
                for (int j = 0; j < 8; ++j)
                    acc[i][j] = fmaf(a[i], w[j], acc[i][j]);
        }
        __syncthreads();
    }

    float* Pb = P + (size_t)blockIdx.y * 64 * O;
#pragma unroll
    for (int i = 0; i < 4; ++i) {
        const float4 v0 = make_float4(acc[i][0], acc[i][1], acc[i][2], acc[i][3]);
        const float4 v1 = make_float4(acc[i][4], acc[i][5], acc[i][6], acc[i][7]);
        *reinterpret_cast<float4*>(Pb + (size_t)(b0 + i) * O + obase + o0) = v0;
        *reinterpret_cast<float4*>(Pb + (size_t)(b0 + i) * O + obase + o0 + 4) = v1;
    }
}

// ---------------------------------------------------------------------------
// GEMM with A built from NPART partials + bias (+optional ReLU):
// A[b][k] = act(abias[k] + sum_s Pa[s][b][k]).  Same tiling as gemm_proj.
// ---------------------------------------------------------------------------
template <int K, int KS, int NPART, bool RELU_A>
__global__ __launch_bounds__(256) void gemm_psum(
    const float* __restrict__ Pa,     // [NPART][64][K]
    const float* __restrict__ abias,  // [K]
    const float* __restrict__ W,      // [O][K]
    float* __restrict__ P)            // [KS][64][O]
{
    constexpr int KSUB = K / KS;
    const int O = gridDim.x * 128;
    const int obase = blockIdx.x * 128;
    const int kb = blockIdx.y * KSUB;
    const int tid = threadIdx.x;

    __shared__ float As[32][68];
    __shared__ float Ws[32][132];

    const int b0 = (tid >> 4) * 4;
    const int o0 = (tid & 15) * 8;

    float acc[4][8];
#pragma unroll
    for (int i = 0; i < 4; ++i)
#pragma unroll
        for (int j = 0; j < 8; ++j) acc[i][j] = 0.f;

    for (int kc = 0; kc < KSUB; kc += 32) {
#pragma unroll
        for (int j = 0; j < 2; ++j) {
            const int f = tid + 256 * j;
            const int bb = f >> 3, k4 = f & 7;
            const int kg = kb + kc + 4 * k4;
            float4 v = *reinterpret_cast<const float4*>(abias + kg);
#pragma unroll
            for (int s = 0; s < NPART; ++s)
                v = f4add(v, *reinterpret_cast<const float4*>(
                    Pa + (size_t)(s * 64 + bb) * K + kg));
            if (RELU_A) {
                v.x = fmaxf(v.x, 0.f); v.y = fmaxf(v.y, 0.f);
                v.z = fmaxf(v.z, 0.f); v.w = fmaxf(v.w, 0.f);
            }
            As[4 * k4 + 0][bb] = v.x; As[4 * k4 + 1][bb] = v.y;
            As[4 * k4 + 2][bb] = v.z; As[4 * k4 + 3][bb] = v.w;
        }
#pragma unroll
        for (int j = 0; j < 4; ++j) {
            const int f = tid + 256 * j;
            const int oo = f >> 3, k4 = f & 7;
            const float4 v = *reinterpret_cast<const float4*>(
                W + (size_t)(obase + oo) * K + kb + kc + 4 * k4);
            Ws[4 * k4 + 0][oo] = v.x; Ws[4 * k4 + 1][oo] = v.y;
            Ws[4 * k4 + 2][oo] = v.z; Ws[4 * k4 + 3][oo] = v.w;
        }
        __syncthreads();
#pragma unroll 8
        for (int k = 0; k < 32; ++k) {
            const float4 av = *reinterpret_cast<const float4*>(&As[k][b0]);
            const float4 w0 = *reinterpret_cast<const float4*>(&Ws[k][o0]);
            const float4 w1 = *reinterpret_cast<const float4*>(&Ws[k][o0 + 4]);
            const float a[4] = {av.x, av.y, av.z, av.w};
            const float w[8] = {w0.x, w0.y, w0.z, w0.w, w1.x, w1.y, w1.z, w1.w};
#pragma unroll
            for (int i = 0; i < 4; ++i)
#pragma unroll
                for (int j = 0; j < 8; ++j)
                    acc[i][j] = fmaf(a[i], w[j], acc[i][j]);
        }
        __syncthreads();
    }

    float* Pb = P + (size_t)blockIdx.y * 64 * O;
#pragma unroll
    for (int i = 0; i < 4; ++i) {
        const float4 v0 = make_float4(acc[i][0], acc[i][1], acc[i][2], acc[i][3]);
        const float4 v1 = make_float4(acc[i][4], acc[i][5], acc[i][6], acc[i][7]);
        *reinterpret_cast<float4*>(Pb + (size_t)(b0 + i) * O + obase + o0) = v0;
        *reinterpret_cast<float4*>(Pb + (size_t)(b0 + i) * O + obase + o0 + 4) = v1;
    }
}

// ---------------------------------------------------------------------------
// u[b,h,:] = sum_k q[b,h,k] * Wk[h*64+k][:], q = sum_{s<16} Pq[s] + bq fused.
// grid (H, 8), block 256, thread tile 4b x 8d.
// ---------------------------------------------------------------------------
__global__ __launch_bounds__(256) void gemm_u(
    const float* __restrict__ Pq,   // [16][64][D]
    const float* __restrict__ bq,   // [D]
    const float* __restrict__ Wk,   // [D][D]
    float* __restrict__ u)
{
    const int h = blockIdx.x;
    const int dbase = blockIdx.y * 128;
    const int tid = threadIdx.x;

    __shared__ float As[32][68];
    __shared__ float Ws[32][132];

    const int b0 = (tid >> 4) * 4;
    const int o0 = (tid & 15) * 8;

    float acc[4][8];
#pragma unroll
    for (int i = 0; i < 4; ++i)
#pragma unroll
        for (int j = 0; j < 8; ++j) acc[i][j] = 0.f;

    for (int kc = 0; kc < DH; kc += 32) {
#pragma unroll
        for (int j = 0; j < 2; ++j) {
            const int f = tid + 256 * j;
            const int bb = f >> 3, k4 = f & 7;
            const int kg = h * DH + kc + 4 * k4;
            float4 v = *reinterpret_cast<const float4*>(bq + kg);
#pragma unroll
            for (int s = 0; s < 16; ++s)
                v = f4add(v, *reinterpret_cast<const float4*>(
                    Pq + (size_t)(s * 64 + bb) * D + kg));
            As[4 * k4 + 0][bb] = v.x; As[4 * k4 + 1][bb] = v.y;
            As[4 * k4 + 2][bb] = v.z; As[4 * k4 + 3][bb] = v.w;
        }
#pragma unroll
        for (int j = 0; j < 4; ++j) {
            const int f = tid + 256 * j;
            const int k = f >> 5, d4 = f & 31;
            const float4 v = *reinterpret_cast<const float4*>(
                Wk + (size_t)(h * DH + kc + k) * D + dbase + 4 * d4);
            *reinterpret_cast<float4*>(&Ws[k][4 * d4]) = v;
        }
        __syncthreads();
#pragma unroll 8
        for (int k = 0; k < 32; ++k) {
            const float4 av = *reinterpret_cast<const float4*>(&As[k][b0]);
            const float4 w0 = *reinterpret_cast<const float4*>(&Ws[k][o0]);
            const float4 w1 = *reinterpret_cast<const float4*>(&Ws[k][o0 + 4]);
            const float a[4] = {av.x, av.y, av.z, av.w};
            const float w[8] = {w0.x, w0.y, w0.z, w0.w, w1.x, w1.y, w1.z, w1.w};
#pragma unroll
            for (int i = 0; i < 4; ++i)
#pragma unroll
                for (int j = 0; j < 8; ++j)
                    acc[i][j] = fmaf(a[i], w[j], acc[i][j]);
        }
        __syncthreads();
    }
#pragma unroll
    for (int i = 0; i < 4; ++i) {
        const float4 v0 = make_float4(acc[i][0], acc[i][1], acc[i][2], acc[i][3]);
        const float4 v1 = make_float4(acc[i][4], acc[i][5], acc[i][6], acc[i][7]);
        float* ur = u + ((size_t)(b0 + i) * H + h) * D + dbase + o0;
        *reinterpret_cast<float4*>(ur) = v0;
        *reinterpret_cast<float4*>(ur + 4) = v1;
    }
}

// ---------------------------------------------------------------------------
// Fused streaming self-attention (layers >= 1): single pass over the cache.
// grid (B, 4) - 128 tokens per block. block 512: thread (h=tid>>5, seg=tid&31).
// 2-token stages: float4 global loads, 1 barrier per 2 tokens.
// ---------------------------------------------------------------------------
__global__ __launch_bounds__(512) void sattn_kernel(
    const float* __restrict__ cache_i, const float* __restrict__ x,
    const float* __restrict__ u, float* __restrict__ wpart4,
    float* __restrict__ sums)
{
    const int b = blockIdx.x, th = blockIdx.y;
    const int tid = threadIdx.x;
    const int h = tid >> 5, seg = tid & 31;

    float4 ur[8];
    const float* ub = u + ((size_t)(b * H + h)) * D;
#pragma unroll
    for (int c = 0; c < 8; ++c) {
        const float4 v = *reinterpret_cast<const float4*>(ub + c * 128 + seg * 4);
        ur[c] = make_float4(v.x * SCALE, v.y * SCALE, v.z * SCALE, v.w * SCALE);
    }
    float4 ar[8];
#pragma unroll
    for (int c = 0; c < 8; ++c) ar[c] = make_float4(0.f, 0.f, 0.f, 0.f);
    float sumE = 0.f;

    __shared__ float rowb[2][2][1024];

    const int tg0 = th * 128;
    const int lr = tid >> 8;          // which of the 2 staged rows
    const int lc = (tid & 255) * 4;   // col

    auto rowptr = [&](int t) -> const float* {
        return (t < T) ? cache_i + ((size_t)t * B + b) * D : x + (size_t)b * D;
    };
    float4 pre = *reinterpret_cast<const float4*>(rowptr(tg0 + lr) + lc);

    for (int st = 0; st < 64; ++st) {
        const int p = st & 1;
        *reinterpret_cast<float4*>(&rowb[p][lr][lc]) = pre;
        __syncthreads();
        if (st + 1 < 64)
            pre = *reinterpret_cast<const float4*>(
                rowptr(tg0 + 2 * (st + 1) + lr) + lc);
#pragma unroll
        for (int r = 0; r < 2; ++r) {
            float4 rv[8];
            float dot = 0.f;
#pragma unroll
            for (int c = 0; c < 8; ++c) {
                rv[c] = *reinterpret_cast<const float4*>(
                    &rowb[p][r][c * 128 + seg * 4]);
                dot += dot4(ur[c], rv[c]);
            }
#pragma unroll
            for (int m = 16; m >= 1; m >>= 1) dot += __shfl_xor(dot, m, 64);
            const float e = __expf(dot);
            sumE += e;
#pragma unroll
            for (int c = 0; c < 8; ++c) {
                ar[c].x = fmaf(e, rv[c].x, ar[c].x);
                ar[c].y = fmaf(e, rv[c].y, ar[c].y);
                ar[c].z = fmaf(e, rv[c].z, ar[c].z);
                ar[c].w = fmaf(e, rv[c].w, ar[c].w);
            }
        }
    }

    float* wp = wpart4 + (((size_t)(b * 4 + th)) * H + h) * D;
#pragma unroll
    for (int c = 0; c < 8; ++c)
        *reinterpret_cast<float4*>(wp + c * 128 + seg * 4) = ar[c];
    if (seg == 0) sums[(b * 4 + th) * H + h] = sumE;
}

// ---------------------------------------------------------------------------
// ctx partial: P[ks][b][h*64+o] = sum_d wn[b,h,d]*Wv[h*64+o][d]
// A-staging fuses the 4 t-partials and the 1/sumE normalization.
// grid (H, 8), block 256, thread tile 4b x 4o.
// ---------------------------------------------------------------------------
__global__ __launch_bounds__(256) void gemm_ctx8(
    const float* __restrict__ wpart4, const float* __restrict__ sums,
    const float* __restrict__ Wv, float* __restrict__ P)
{
    constexpr int KSUB = D / 8;   // 128
    const int h = blockIdx.x;
    const int kb = blockIdx.y * KSUB;
    const int tid = threadIdx.x;

    __shared__ float As[32][68];
    __shared__ float Ws[32][68];
    __shared__ float sinv[64];

    if (tid < 64) {
        float s = 0.f;
#pragma unroll
        for (int t = 0; t < 4; ++t) s += sums[(tid * 4 + t) * H + h];
        sinv[tid] = 1.f / s;
    }
    __syncthreads();

    const int b0 = (tid >> 4) * 4;
    const int o0 = (tid & 15) * 4;

    float acc[4][4];
#pragma unroll
    for (int i = 0; i < 4; ++i)
#pragma unroll
        for (int j = 0; j < 4; ++j) acc[i][j] = 0.f;

    for (int kc = 0; kc < KSUB; kc += 32) {
#pragma unroll
        for (int j = 0; j < 2; ++j) {
            const int f = tid + 256 * j;
            const int bb = f >> 3, k4 = f & 7;
            const int kg = kb + kc + 4 * k4;
            float4 v = make_float4(0.f, 0.f, 0.f, 0.f);
#pragma unroll
            for (int t = 0; t < 4; ++t)
                v = f4add(v, *reinterpret_cast<const float4*>(
                    wpart4 + (((size_t)(bb * 4 + t)) * H + h) * D + kg));
            const float iv = sinv[bb];
            As[4 * k4 + 0][bb] = v.x * iv; As[4 * k4 + 1][bb] = v.y * iv;
            As[4 * k4 + 2][bb] = v.z * iv; As[4 * k4 + 3][bb] = v.w * iv;
        }
#pragma unroll
        for (int j = 0; j < 2; ++j) {
            const int f = tid + 256 * j;
            const int oo = f >> 3, k4 = f & 7;
            const float4 v = *reinterpret_cast<const float4*>(
                Wv + (size_t)(h * DH + oo) * D + kb + kc + 4 * k4);
            Ws[4 * k4 + 0][oo] = v.x; Ws[4 * k4 + 1][oo] = v.y;
            Ws[4 * k4 + 2][oo] = v.z; Ws[4 * k4 + 3][oo] = v.w;
        }
        __syncthreads();
#pragma unroll 8
        for (int k = 0; k < 32; ++k) {
            const float4 av = *reinterpret_cast<const float4*>(&As[k][b0]);
            const float4 wv = *reinterpret_cast<const float4*>(&Ws[k][o0]);
            const float a[4] = {av.x, av.y, av.z, av.w};
            const float w[4] = {wv.x, wv.y, wv.z, wv.w};
#pragma unroll
            for (int i = 0; i < 4; ++i)
#pragma unroll
                for (int j = 0; j < 4; ++j)
                    acc[i][j] = fmaf(a[i], w[j], acc[i][j]);
        }
        __syncthreads();
    }
    float* Pb = P + (size_t)blockIdx.y * 64 * D;
#pragma unroll
    for (int i = 0; i < 4; ++i) {
        const float4 v = make_float4(acc[i][0], acc[i][1], acc[i][2], acc[i][3]);
        *reinterpret_cast<float4*>(Pb + (size_t)(b0 + i) * D + h * DH + o0) = v;
    }
}

// ---------------------------------------------------------------------------
// finish + residual + LayerNorm (O=D). grid B, block 256.
// ---------------------------------------------------------------------------
template <int KS>
__global__ __launch_bounds__(256) void finish_ln(
    const float* __restrict__ P, const float* __restrict__ bias,
    const float* __restrict__ resid, const float* __restrict__ g,
    const float* __restrict__ bb, float* __restrict__ out)
{
    const int b = blockIdx.x, tid = threadIdx.x;
    const float4* P4 = reinterpret_cast<const float4*>(P);
    float4 v = reinterpret_cast<const float4*>(bias)[tid];
    v = f4add(v, reinterpret_cast<const float4*>(resid + (size_t)b * D)[tid]);
#pragma unroll
    for (int s = 0; s < KS; ++s)
        v = f4add(v, P4[(size_t)(s * 64 + b) * 256 + tid]);

    float ssum = v.x + v.y + v.z + v.w;
#pragma unroll
    for (int m = 32; m >= 1; m >>= 1) ssum += __shfl_xor(ssum, m, 64);
    __shared__ float red[4];
    if ((tid & 63) == 0) red[tid >> 6] = ssum;
    __syncthreads();
    const float mean = (red[0] + red[1] + red[2] + red[3]) * (1.f / D);
    const float dx = v.x - mean, dy = v.y - mean, dz = v.z - mean, dw = v.w - mean;
    float q = dx * dx + dy * dy + dz * dz + dw * dw;
#pragma unroll
    for (int m = 32; m >= 1; m >>= 1) q += __shfl_xor(q, m, 64);
    __shared__ float red2[4];
    if ((tid & 63) == 0) red2[tid >> 6] = q;
    __syncthreads();
    const float var = (red2[0] + red2[1] + red2[2] + red2[3]) * (1.f / D);
    const float rs = rsqrtf(var + EPS);
    const float4 gv = reinterpret_cast<const float4*>(g)[tid];
    const float4 bv = reinterpret_cast<const float4*>(bb)[tid];
    float4 o;
    o.x = dx * rs * gv.x + bv.x;
    o.y = dy * rs * gv.y + bv.y;
    o.z = dz * rs * gv.z + bv.z;
    o.w = dw * rs * gv.w + bv.w;
    reinterpret_cast<float4*>(out + (size_t)b * D)[tid] = o;
}

// ---------------------------------------------------------------------------
// Fused attention. q (and for HASX the extra k/v row) built from split-K
// partials + bias in LDS. grid (B,H), block 256.
// qP: [qnp][64][qpitch]; qbias: [qpitch] (layer0: q|k|v concatenated).
// ---------------------------------------------------------------------------
template <int NS, bool HASX>
__global__ __launch_bounds__(256) void attn_kernel(
    const float* __restrict__ qP, const float* __restrict__ qbias,
    int qnp, int qpitch,
    const float* __restrict__ Kb, const float* __restrict__ Vb,
    float* __restrict__ ctx, int nk)
{
    const int b = blockIdx.x, h = blockIdx.y, tid = threadIdx.x;
    __shared__ float qs[DH];
    __shared__ float kx[DH];
    __shared__ float vx[DH];
    __shared__ float sa[NS];
    if (tid < DH) {
        const int col = h * DH + tid;
        float v = qbias[col];
        for (int s = 0; s < qnp; ++s)
            v += qP[(size_t)(s * 64 + b) * qpitch + col];
        qs[tid] = v;
        if (HASX) {
            float kk = qbias[D + col];
            float vv = qbias[2 * D + col];
            for (int s = 0; s < qnp; ++s) {
                const float* base = qP + (size_t)(s * 64 + b) * qpitch + col;
                kk += base[D];
                vv += base[2 * D];
            }
            kx[tid] = kk; vx[tid] = vv;
        }
    }
    __syncthreads();

    const int ss = tid >> 2, p = tid & 3;
    const float* Kbh = Kb + ((size_t)(b * H + h)) * nk * DH;
#pragma unroll 2
    for (int pass = 0; pass < NS / 64; ++pass) {
        const int s = pass * 64 + ss;
        const float* row = (!HASX || s < nk) ? (Kbh + (size_t)s * DH)
                                             : (const float*)kx;
        const float4* rp = reinterpret_cast<const float4*>(row);
        const float4* qp = reinterpret_cast<const float4*>(qs) + p * 4;
        float acc = 0.f;
#pragma unroll
        for (int c = 0; c < 4; ++c) acc += dot4(rp[p * 4 + c], qp[c]);
        acc += __shfl_xor(acc, 1, 64);
        acc += __shfl_xor(acc, 2, 64);
        if (p == 0) sa[s] = acc * SCALE;
    }
    __syncthreads();

    float m = -1e30f;
    for (int k = tid; k < NS; k += 256) m = fmaxf(m, sa[k]);
#pragma unroll
    for (int mm = 32; mm >= 1; mm >>= 1) m = fmaxf(m, __shfl_xor(m, mm, 64));
    __shared__ float r1[4];
    if ((tid & 63) == 0) r1[tid >> 6] = m;
    __syncthreads();
    m = fmaxf(fmaxf(r1[0], r1[1]), fmaxf(r1[2], r1[3]));
    float sum = 0.f;
    for (int k = tid; k < NS; k += 256) {
        const float e = __expf(sa[k] - m);
        sa[k] = e;
        sum += e;
    }
#pragma unroll
    for (int mm = 32; mm >= 1; mm >>= 1) sum += __shfl_xor(sum, mm, 64);
    __shared__ float r2[4];
    if ((tid & 63) == 0) r2[tid >> 6] = sum;
    __syncthreads();
    const float inv = 1.f / (r2[0] + r2[1] + r2[2] + r2[3]);

    const int dh4 = tid & 15, sq = tid >> 4;
    const float* Vbh = Vb + ((size_t)(b * H + h)) * nk * DH;
    float4 acc = make_float4(0.f, 0.f, 0.f, 0.f);
#pragma unroll 2
    for (int s = sq; s < NS; s += 16) {
        const float* row = (!HASX || s < nk) ? (Vbh + (size_t)s * DH)
                                             : (const float*)vx;
        const float4 vv = *reinterpret_cast<const float4*>(row + dh4 * 4);
        const float av = sa[s];
        acc.x += av * vv.x; acc.y += av * vv.y;
        acc.z += av * vv.z; acc.w += av * vv.w;
    }
    __shared__ float red[16 * 68];
    *reinterpret_cast<float4*>(&red[sq * 68 + dh4 * 4]) = acc;
    __syncthreads();
    if (tid < 64) {
        float t = 0.f;
#pragma unroll
        for (int k = 0; k < 16; ++k) t += red[k * 68 + tid];
        ctx[(size_t)b * D + h * DH + tid] = t * inv;
    }
}

// ---------------------------------------------------------------------------
extern "C" void kernel_launch(void* const* d_in, const int* in_sizes, int n_in,
                              void* d_out, int out_size, void* d_ws, size_t ws_size,
                              hipStream_t stream)
{
    const float* tgt_last = (const float*)d_in[0];
    const float* cache    = (const float*)d_in[1];
    const float* K0       = (const float*)d_in[2];
    const float* V0       = (const float*)d_in[3];
    const float* K_mem    = (const float*)d_in[4];
    const float* V_mem    = (const float*)d_in[5];
    const float* sa_W     = (const float*)d_in[6];
    const float* sa_b     = (const float*)d_in[7];
    const float* sa_oW    = (const float*)d_in[8];
    const float* sa_ob    = (const float*)d_in[9];
    const float* ca_qW    = (const float*)d_in[10];
    const float* ca_qb    = (const float*)d_in[11];
    const float* ca_oW    = (const float*)d_in[12];
    const float* ca_ob    = (const float*)d_in[13];
    const float* W1       = (const float*)d_in[14];
    const float* b1       = (const float*)d_in[15];
    const float* W2       = (const float*)d_in[16];
    const float* b2       = (const float*)d_in[17];
    const float* ln1_g    = (const float*)d_in[18];
    const float* ln1_b    = (const float*)d_in[19];
    const float* ln2_g    = (const float*)d_in[20];
    const float* ln2_b    = (const float*)d_in[21];
    const float* ln3_g    = (const float*)d_in[22];
    const float* ln3_b    = (const float*)d_in[23];

    float* ws = (float*)d_ws;
    float* x_buf   = ws;                 // 65536
    float* ctx_buf = ws + 65536;         // 65536
    float* u_buf   = ws + 131072;        // 1048576
    float* wpart4  = ws + 1179648;       // 4194304
    float* sums    = ws + 5373952;       // 4096
    float* Pq      = ws + 5378048;       // 16*B*D = 1048576
    float* PqA     = ws + 6426624;       // 32*B*D = 2097152
    float* Pqkv    = ws + 8523776;       // 8*B*3D = 1572864
    float* Pc      = ws + 10096640;      // 8*B*D = 524288
    float* Pffn    = ws + 10620928;      // 8*B*DFF = 2097152
    float* Pffn2   = ws + 12718080;      // 32*B*D = 2097152

    const dim3 blk(256);

    for (int i = 0; i < NLAYER; ++i) {
        const float* Wq   = sa_W + (size_t)i * 3 * D * D;
        const float* bqkv = sa_b + (size_t)i * 3 * D;

        if (i == 0) {
            gemm_proj<D, 8><<<dim3(24, 8), blk, 0, stream>>>(tgt_last, Wq, Pqkv);
            attn_kernel<TT, true><<<dim3(B, H), blk, 0, stream>>>(
                Pqkv, bqkv, 8, 3 * D, K0, V0, ctx_buf, T);
            gemm_proj<D, 32><<<dim3(8, 32), blk, 0, stream>>>(
                ctx_buf, sa_oW + (size_t)i * D * D, PqA);
            finish_ln<32><<<dim3(B), blk, 0, stream>>>(
                PqA, sa_ob + (size_t)i * D, tgt_last,
                ln1_g + (size_t)i * D, ln1_b + (size_t)i * D, x_buf);
        } else {
            const float* cache_i = cache + (size_t)i * T * B * D;
            gemm_proj<D, 16><<<dim3(8, 16), blk, 0, stream>>>(x_buf, Wq, Pq);
            gemm_u<<<dim3(H, 8), blk, 0, stream>>>(
                Pq, bqkv, Wq + (size_t)D * D, u_buf);
            sattn_kernel<<<dim3(B, 4), dim3(512), 0, stream>>>(
                cache_i, x_buf, u_buf, wpart4, sums);
            gemm_ctx8<<<dim3(H, 8), blk, 0, stream>>>(
                wpart4, sums, Wq + (size_t)2 * D * D, Pc);
            gemm_psum<D, 32, 8, false><<<dim3(8, 32), blk, 0, stream>>>(
                Pc, bqkv + 2 * D, sa_oW + (size_t)i * D * D, PqA);
            finish_ln<32><<<dim3(B), blk, 0, stream>>>(
                PqA, sa_ob + (size_t)i * D, x_buf,
                ln1_g + (size_t)i * D, ln1_b + (size_t)i * D, x_buf);
        }

        // cross attention
        gemm_proj<D, 32><<<dim3(8, 32), blk, 0, stream>>>(
            x_buf, ca_qW + (size_t)i * D * D, PqA);
        attn_kernel<SMEM, false><<<dim3(B, H), blk, 0, stream>>>(
            PqA, ca_qb + (size_t)i * D, 32, D,
            K_mem + (size_t)i * B * H * SMEM * DH,
            V_mem + (size_t)i * B * H * SMEM * DH, ctx_buf, SMEM);
        gemm_proj<D, 32><<<dim3(8, 32), blk, 0, stream>>>(
            ctx_buf, ca_oW + (size_t)i * D * D, PqA);
        finish_ln<32><<<dim3(B), blk, 0, stream>>>(
            PqA, ca_ob + (size_t)i * D, x_buf,
            ln2_g + (size_t)i * D, ln2_b + (size_t)i * D, x_buf);

        // FFN
        gemm_proj<D, 8><<<dim3(32, 8), blk, 0, stream>>>(
            x_buf, W1 + (size_t)i * DFF * D, Pffn);
        gemm_psum<DFF, 32, 8, true><<<dim3(8, 32), blk, 0, stream>>>(
            Pffn, b1 + (size_t)i * DFF, W2 + (size_t)i * D * DFF, Pffn2);
        float* lnout = (i == NLAYER - 1) ? (float*)d_out : x_buf;
        finish_ln<32><<<dim3(B), blk, 0, stream>>>(
            Pffn2, b2 + (size_t)i * D, x_buf,
            ln3_g + (size_t)i * D, ln3_b + (size_t)i * D, lnout);
    }
}